// Round 1
// baseline (492.265 us; speedup 1.0000x reference)
//
#include <hip/hip_runtime.h>
#include <hip/hip_bf16.h>

#define NUM_HEADS 32
#define NUM_KV 8
#define GQA 4
#define HD 128
#define BM 64          // q rows per block
#define BN 64          // keys per k-tile
#define MAXS 1024

typedef unsigned short u16;
typedef unsigned int u32;
typedef __attribute__((ext_vector_type(8))) short bf16x8;
typedef __attribute__((ext_vector_type(4))) float f32x4;

__device__ __forceinline__ u16 f2bf(float f) {
    __hip_bfloat16 h = __float2bfloat16(f);
    return __builtin_bit_cast(u16, h);
}

// ---------------- cache copy + scatter ----------------

__global__ void cache_copy(const float4* __restrict__ kci, const float4* __restrict__ vci,
                           float4* __restrict__ kco, float4* __restrict__ vco, int n4) {
    int i = blockIdx.x * blockDim.x + threadIdx.x;
    int stride = gridDim.x * blockDim.x;
    for (; i < n4; i += stride) {
        kco[i] = kci[i];
        vco[i] = vci[i];
    }
}

__global__ void kv_scatter(const float4* __restrict__ k, const float4* __restrict__ v,
                           const int* __restrict__ slots,
                           float4* __restrict__ kco, float4* __restrict__ vco, int nslots) {
    int t = blockIdx.x;
    int s = slots[t];
    if (s < 0 || s >= nslots) return;
    int i = threadIdx.x;                      // 256 == NUM_KV*HD/4 exactly
    kco[(size_t)s * 256 + i] = k[(size_t)t * 256 + i];
    vco[(size_t)s * 256 + i] = v[(size_t)t * 256 + i];
}

// ---------------- flash attention ----------------
// grid: (MAXS/BM, nseq, NUM_KV); block: 512 (8 waves)
// wave w: q-head kvh*4 + (w&3), row-half (w>>2) of the 64-row q tile.

__global__ __launch_bounds__(512, 2) void attn_kernel(
    const float* __restrict__ q, const float* __restrict__ kk, const float* __restrict__ vv,
    const int* __restrict__ cu_q, const int* __restrict__ cu_k,
    float* __restrict__ out)
{
    __shared__ __align__(16) u16 Kt[BN * 136];      // [key][dim], padded+swizzled
    __shared__ __align__(16) u16 Vt[HD * 72];       // [dim][key], padded+swizzled
    __shared__ __align__(16) u16 Pb[8 * 16 * 72];   // per-wave P round-trip (16 rows)

    const int qt = blockIdx.x, b = blockIdx.y, kvh = blockIdx.z;
    const int q0 = cu_q[b];
    const int Lq = cu_q[b + 1] - q0;
    const int k0 = cu_k[b];
    const int Lk = cu_k[b + 1] - k0;
    const int qbase = qt * BM;
    if (qbase >= Lq) return;

    const int tid = threadIdx.x;
    const int wave = tid >> 6;
    const int lane = tid & 63;
    const int c = lane & 15;
    const int quad = lane >> 4;
    const int h = kvh * GQA + (wave & 3);
    const int rhalf = wave >> 2;
    const int wrow0 = qbase + rhalf * 32;

    // ---- Q fragments (scale * log2e folded in) ----
    const float qs = 0.08838834764831845f * 1.44269504088896340f;
    bf16x8 qf[2][4];
#pragma unroll
    for (int rt = 0; rt < 2; ++rt) {
        int row = wrow0 + rt * 16 + c;
        int tok = q0 + (row < Lq ? row : Lq - 1);
        const float* qp = q + ((size_t)tok * NUM_HEADS + h) * HD + quad * 8;
#pragma unroll
        for (int kc = 0; kc < 4; ++kc) {
            float4 x = *(const float4*)(qp + kc * 32);
            float4 y = *(const float4*)(qp + kc * 32 + 4);
            union { bf16x8 v; u16 s[8]; } u;
            u.s[0] = f2bf(x.x * qs); u.s[1] = f2bf(x.y * qs);
            u.s[2] = f2bf(x.z * qs); u.s[3] = f2bf(x.w * qs);
            u.s[4] = f2bf(y.x * qs); u.s[5] = f2bf(y.y * qs);
            u.s[6] = f2bf(y.z * qs); u.s[7] = f2bf(y.w * qs);
            qf[rt][kc] = u.v;
        }
    }

    f32x4 Oacc[2][8];
    f32x4 m_i[2], l_i[2];
#pragma unroll
    for (int rt = 0; rt < 2; ++rt) {
        m_i[rt] = (f32x4)(-3.0e38f);
        l_i[rt] = (f32x4)(0.0f);
#pragma unroll
        for (int nt = 0; nt < 8; ++nt) Oacc[rt][nt] = (f32x4)(0.0f);
    }

    const int kmax = min(qbase + BM, Lk);
    const int ntile = (kmax + BN - 1) / BN;
    const int stkey = tid >> 3;     // K staging: 64 keys x 8 dim-groups
    const int stg = tid & 7;

    for (int it = 0; it < ntile; ++it) {
        const int kbase = it * BN;
        __syncthreads();
        // ---- stage K tile (row-major, bf16, swizzled granules) ----
        {
            int kp = kbase + stkey;
            int tok = k0 + (kp < Lk ? kp : Lk - 1);
            const float* kg = kk + ((size_t)tok * NUM_KV + kvh) * HD + stg * 16;
            float4 a = ((const float4*)kg)[0];
            float4 b4 = ((const float4*)kg)[1];
            float4 c4 = ((const float4*)kg)[2];
            float4 d4 = ((const float4*)kg)[3];
            u32 p0 = f2bf(a.x)  | ((u32)f2bf(a.y)  << 16);
            u32 p1 = f2bf(a.z)  | ((u32)f2bf(a.w)  << 16);
            u32 p2 = f2bf(b4.x) | ((u32)f2bf(b4.y) << 16);
            u32 p3 = f2bf(b4.z) | ((u32)f2bf(b4.w) << 16);
            u32 p4 = f2bf(c4.x) | ((u32)f2bf(c4.y) << 16);
            u32 p5 = f2bf(c4.z) | ((u32)f2bf(c4.w) << 16);
            u32 p6 = f2bf(d4.x) | ((u32)f2bf(d4.y) << 16);
            u32 p7 = f2bf(d4.z) | ((u32)f2bf(d4.w) << 16);
            int g0 = (2 * stg)     ^ (stkey & 7);
            int g1 = (2 * stg + 1) ^ (stkey & 7);
            *(uint4*)&Kt[stkey * 136 + g0 * 8] = make_uint4(p0, p1, p2, p3);
            *(uint4*)&Kt[stkey * 136 + g1 * 8] = make_uint4(p4, p5, p6, p7);
        }
        // ---- stage V tile transposed (dim-major; lane<->key => conflict-free writes) ----
        {
            int vp = kbase + lane;
            int tok = k0 + (vp < Lk ? vp : Lk - 1);
            const float* vg = vv + ((size_t)tok * NUM_KV + kvh) * HD + wave * 16;
            int kb = lane >> 3, ko = lane & 7;
#pragma unroll
            for (int i = 0; i < 4; ++i) {
                float4 x = ((const float4*)vg)[i];
                int dim = wave * 16 + i * 4;
                Vt[(dim + 0) * 72 + ((kb ^ ((dim + 0) & 7)) * 8) + ko] = f2bf(x.x);
                Vt[(dim + 1) * 72 + ((kb ^ ((dim + 1) & 7)) * 8) + ko] = f2bf(x.y);
                Vt[(dim + 2) * 72 + ((kb ^ ((dim + 2) & 7)) * 8) + ko] = f2bf(x.z);
                Vt[(dim + 3) * 72 + ((kb ^ ((dim + 3) & 7)) * 8) + ko] = f2bf(x.w);
            }
        }
        __syncthreads();

        // ---- S = Q K^T ----
        f32x4 S[2][4];
#pragma unroll
        for (int rt = 0; rt < 2; ++rt)
#pragma unroll
            for (int nt = 0; nt < 4; ++nt) S[rt][nt] = (f32x4)(0.0f);
#pragma unroll
        for (int nt = 0; nt < 4; ++nt) {
            int key = nt * 16 + c;
#pragma unroll
            for (int kc = 0; kc < 4; ++kc) {
                bf16x8 kf = *(const bf16x8*)&Kt[key * 136 + (((kc * 4 + quad) ^ (c & 7)) * 8)];
                S[0][nt] = __builtin_amdgcn_mfma_f32_16x16x32_bf16(qf[0][kc], kf, S[0][nt], 0, 0, 0);
                S[1][nt] = __builtin_amdgcn_mfma_f32_16x16x32_bf16(qf[1][kc], kf, S[1][nt], 0, 0, 0);
            }
        }

        // ---- online softmax + P round-trip, per 16-row tile ----
        bf16x8 pf[2][2];
#pragma unroll
        for (int rt = 0; rt < 2; ++rt) {
            int rtb = wrow0 + rt * 16;
            bool notfull = !((kbase + BN <= rtb + 1) && (kbase + BN <= Lk));
            if (notfull) {
                int qp4 = rtb + quad * 4;
#pragma unroll
                for (int nt = 0; nt < 4; ++nt) {
                    int kp = kbase + nt * 16 + c;
                    bool kval = kp < Lk;
#pragma unroll
                    for (int r = 0; r < 4; ++r)
                        if (!(kval && kp <= qp4 + r)) S[rt][nt][r] = -3.0e38f;
                }
            }
            f32x4 rm;
#pragma unroll
            for (int r = 0; r < 4; ++r)
                rm[r] = fmaxf(fmaxf(S[rt][0][r], S[rt][1][r]), fmaxf(S[rt][2][r], S[rt][3][r]));
#pragma unroll
            for (int d2 = 1; d2 < 16; d2 <<= 1)
#pragma unroll
                for (int r = 0; r < 4; ++r)
                    rm[r] = fmaxf(rm[r], __shfl_xor(rm[r], d2));
            f32x4 mn, al;
#pragma unroll
            for (int r = 0; r < 4; ++r) {
                mn[r] = fmaxf(m_i[rt][r], rm[r]);
                al[r] = exp2f(m_i[rt][r] - mn[r]);
            }
            m_i[rt] = mn;
            f32x4 rs = (f32x4)(0.0f);
#pragma unroll
            for (int nt = 0; nt < 4; ++nt)
#pragma unroll
                for (int r = 0; r < 4; ++r) {
                    float p = exp2f(S[rt][nt][r] - mn[r]);
                    S[rt][nt][r] = p;
                    rs[r] += p;
                }
#pragma unroll
            for (int d2 = 1; d2 < 16; d2 <<= 1)
#pragma unroll
                for (int r = 0; r < 4; ++r)
                    rs[r] += __shfl_xor(rs[r], d2);
#pragma unroll
            for (int r = 0; r < 4; ++r)
                l_i[rt][r] = l_i[rt][r] * al[r] + rs[r];
#pragma unroll
            for (int nt = 0; nt < 8; ++nt)
#pragma unroll
                for (int r = 0; r < 4; ++r)
                    Oacc[rt][nt][r] *= al[r];
            // write P (C-layout), read back as A-layout fragments
            u16* pb = &Pb[wave * (16 * 72)];
#pragma unroll
            for (int nt = 0; nt < 4; ++nt)
#pragma unroll
                for (int r = 0; r < 4; ++r)
                    pb[(quad * 4 + r) * 72 + nt * 16 + c] = f2bf(S[rt][nt][r]);
            asm volatile("s_waitcnt lgkmcnt(0)" ::: "memory");
            pf[rt][0] = *(const bf16x8*)&pb[c * 72 + quad * 8];
            pf[rt][1] = *(const bf16x8*)&pb[c * 72 + 32 + quad * 8];
            asm volatile("" ::: "memory");
        }

        // ---- O += P V ----
#pragma unroll
        for (int nt = 0; nt < 8; ++nt) {
            int dim = nt * 16 + c;
#pragma unroll
            for (int kc = 0; kc < 2; ++kc) {
                bf16x8 vf = *(const bf16x8*)&Vt[dim * 72 + (((kc * 4 + quad) ^ (c & 7)) * 8)];
                Oacc[0][nt] = __builtin_amdgcn_mfma_f32_16x16x32_bf16(pf[0][kc], vf, Oacc[0][nt], 0, 0, 0);
                Oacc[1][nt] = __builtin_amdgcn_mfma_f32_16x16x32_bf16(pf[1][kc], vf, Oacc[1][nt], 0, 0, 0);
            }
        }
    }

    // ---- epilogue: normalize and store ----
#pragma unroll
    for (int rt = 0; rt < 2; ++rt) {
        f32x4 li;
#pragma unroll
        for (int r = 0; r < 4; ++r) li[r] = 1.0f / l_i[rt][r];
#pragma unroll
        for (int r = 0; r < 4; ++r) {
            int row = wrow0 + rt * 16 + quad * 4 + r;
            if (row < Lq) {
                float* op = out + ((size_t)(q0 + row) * NUM_HEADS + h) * HD + c;
#pragma unroll
                for (int nt = 0; nt < 8; ++nt)
                    op[nt * 16] = Oacc[rt][nt][r] * li[r];
            }
        }
    }
}

extern "C" void kernel_launch(void* const* d_in, const int* in_sizes, int n_in,
                              void* d_out, int out_size, void* d_ws, size_t ws_size,
                              hipStream_t stream) {
    const float* q   = (const float*)d_in[0];
    const float* k   = (const float*)d_in[1];
    const float* v   = (const float*)d_in[2];
    const float* kci = (const float*)d_in[3];
    const float* vci = (const float*)d_in[4];
    const int* slot  = (const int*)d_in[5];
    const int* cuq   = (const int*)d_in[6];
    const int* cuk   = (const int*)d_in[7];

    int total  = in_sizes[0] / (NUM_HEADS * HD);
    int nslots = in_sizes[3] / (NUM_KV * HD);
    int nseq   = in_sizes[6] - 1;

    float* out = (float*)d_out;
    float* kco = out + (size_t)total * NUM_HEADS * HD;
    float* vco = kco + (size_t)nslots * NUM_KV * HD;

    int n4 = nslots * NUM_KV * HD / 4;
    cache_copy<<<4096, 256, 0, stream>>>((const float4*)kci, (const float4*)vci,
                                         (float4*)kco, (float4*)vco, n4);
    kv_scatter<<<total, 256, 0, stream>>>((const float4*)k, (const float4*)v, slot,
                                          (float4*)kco, (float4*)vco, nslots);
    attn_kernel<<<dim3(MAXS / BM, nseq, NUM_KV), 512, 0, stream>>>(q, k, v, cuq, cuk, out);
}

// Round 2
// 399.287 us; speedup vs baseline: 1.2329x; 1.2329x over previous
//
#include <hip/hip_runtime.h>
#include <hip/hip_bf16.h>

#define NUM_HEADS 32
#define NUM_KV 8
#define GQA 4
#define HD 128
#define BM 32          // q rows per attn block
#define BN 64          // keys per k-tile
#define MAXS 1024
#define QTMAX (MAXS / BM)   // 32
#define KSTR 136            // Kt row stride (u16): 17 granules -> rotates bank groups by +1/key
#define VSTR 72             // Vt row stride (u16): 9 granules  -> rotates bank groups by +1/dim
#define PSTR 72

typedef unsigned short u16;
typedef unsigned int u32;
typedef __attribute__((ext_vector_type(8))) short bf16x8;
typedef __attribute__((ext_vector_type(4))) float f32x4;
typedef __attribute__((ext_vector_type(4))) float f4v;

__device__ __forceinline__ u16 f2bf(float f) {
    __hip_bfloat16 h = __float2bfloat16(f);
    return __builtin_bit_cast(u16, h);
}

// ---------------- inverse slot map (d_ws) ----------------

__global__ void inv_init(int* __restrict__ inv, int n) {
    int i = blockIdx.x * blockDim.x + threadIdx.x;
    for (; i < n; i += gridDim.x * blockDim.x) inv[i] = -1;
}

__global__ void inv_scatter(const int* __restrict__ slot, int* __restrict__ inv,
                            int total, int nslots) {
    int i = blockIdx.x * blockDim.x + threadIdx.x;
    if (i < total) {
        int s = slot[i];
        if (s >= 0 && s < nslots) inv[s] = i;
    }
}

// ---------------- fused: cache write + flash attention ----------------
// grid: nattn + W blocks of 256 threads. blockIdx interleaved (attn,attn,copy)
// so copy workers co-reside with attention blocks. attn unit u maps qt in
// DESCENDING order (longest-first for the load-imbalance tail).

__global__ __launch_bounds__(256, 2) void fused_kernel(
    const float* __restrict__ q, const float* __restrict__ kk, const float* __restrict__ vv,
    const float* __restrict__ kci, const float* __restrict__ vci,
    const int* __restrict__ inv,
    const int* __restrict__ cu_q, const int* __restrict__ cu_k,
    float* __restrict__ out, float* __restrict__ kco, float* __restrict__ vco,
    int nseq, int nslots, int W, int nattn)
{
    __shared__ __align__(16) u16 Kt[BN * KSTR];        // [key][dim] bf16
    __shared__ __align__(16) u16 Vt[HD * VSTR];        // [dim][key] bf16 (transposed)
    __shared__ __align__(16) u16 Pb[4 * 32 * PSTR];    // per-wave P round-trip (32 rows)

    const int bid = blockIdx.x;
    const int tid = threadIdx.x;

    int u, wid = -1;
    if (bid < 3 * W) {
        int t3 = bid / 3, r3 = bid - 3 * t3;
        if (r3 == 2) { wid = t3; u = -1; }
        else u = t3 * 2 + r3;
    } else {
        u = 2 * W + (bid - 3 * W);
    }

    // ---------------- copy worker path ----------------
    if (wid >= 0) {
        const f4v* k4   = (const f4v*)kk;
        const f4v* v4   = (const f4v*)vv;
        const f4v* kci4 = (const f4v*)kci;
        const f4v* vci4 = (const f4v*)vci;
        f4v* kco4 = (f4v*)kco;
        f4v* vco4 = (f4v*)vco;
        for (int s = wid; s < nslots; s += W) {
            int t = inv[s];                         // block-uniform
            size_t so = (size_t)s * 256 + tid;
            f4v kv, vvv;
            if (t >= 0) {
                size_t to = (size_t)t * 256 + tid;
                kv  = k4[to];
                vvv = v4[to];
            } else {
                kv  = __builtin_nontemporal_load(&kci4[so]);
                vvv = __builtin_nontemporal_load(&vci4[so]);
            }
            __builtin_nontemporal_store(kv,  &kco4[so]);
            __builtin_nontemporal_store(vvv, &vco4[so]);
        }
        return;
    }

    // ---------------- attention path ----------------
    if (u >= nattn) return;
    const int per = nseq * NUM_KV;
    const int qt = QTMAX - 1 - u / per;
    const int inner = u % per;
    const int kvh = inner % NUM_KV;
    const int b = inner / NUM_KV;

    const int q0 = cu_q[b];
    const int Lq = cu_q[b + 1] - q0;
    const int k0 = cu_k[b];
    const int Lk = cu_k[b + 1] - k0;
    const int qbase = qt * BM;
    if (qbase >= Lq) return;

    const int wave = tid >> 6;
    const int lane = tid & 63;
    const int c = lane & 15;
    const int quad = lane >> 4;
    const int h = kvh * GQA + wave;

    // ---- Q fragments (scale * log2e folded in) ----
    const float qs = 0.08838834764831845f * 1.44269504088896340f;
    bf16x8 qf[2][4];
#pragma unroll
    for (int rt = 0; rt < 2; ++rt) {
        int row = qbase + rt * 16 + c;
        int tok = q0 + (row < Lq ? row : Lq - 1);
        const float* qp = q + ((size_t)tok * NUM_HEADS + h) * HD + quad * 8;
#pragma unroll
        for (int kc = 0; kc < 4; ++kc) {
            float4 x = *(const float4*)(qp + kc * 32);
            float4 y = *(const float4*)(qp + kc * 32 + 4);
            union { bf16x8 v; u16 s[8]; } uu;
            uu.s[0] = f2bf(x.x * qs); uu.s[1] = f2bf(x.y * qs);
            uu.s[2] = f2bf(x.z * qs); uu.s[3] = f2bf(x.w * qs);
            uu.s[4] = f2bf(y.x * qs); uu.s[5] = f2bf(y.y * qs);
            uu.s[6] = f2bf(y.z * qs); uu.s[7] = f2bf(y.w * qs);
            qf[rt][kc] = uu.v;
        }
    }

    f32x4 Oacc[2][8];
    f32x4 m_i[2], l_i[2];
#pragma unroll
    for (int rt = 0; rt < 2; ++rt) {
        m_i[rt] = (f32x4)(-3.0e38f);
        l_i[rt] = (f32x4)(0.0f);
#pragma unroll
        for (int nt = 0; nt < 8; ++nt) Oacc[rt][nt] = (f32x4)(0.0f);
    }

    const int kmax = min(qbase + BM, Lk);
    const int ntile = (kmax + BN - 1) / BN;

    // staging decomposition (256 threads)
    const int kst_key = tid >> 2;      // 0..63
    const int kst_g   = tid & 3;       // dim-group of 32 dims
    const int vp2     = tid >> 3;      // 0..31 key-pair
    const int vdg     = tid & 7;       // dim-group of 16 dims
    const int vgran   = vp2 >> 2;      // key granule 0..7
    const int vko     = (vp2 & 3) * 2; // u16 offset within granule

    for (int it = 0; it < ntile; ++it) {
        const int kbase = it * BN;
        __syncthreads();
        // ---- stage K tile [key][dim], natural granule order (stride-136 rotates banks) ----
        {
            int kp = kbase + kst_key;
            int tok = k0 + (kp < Lk ? kp : Lk - 1);
            const float* kg = kk + ((size_t)tok * NUM_KV + kvh) * HD + kst_g * 32;
            u16* krow = &Kt[kst_key * KSTR];
#pragma unroll
            for (int j = 0; j < 4; ++j) {
                float4 x = ((const float4*)kg)[2 * j];
                float4 y = ((const float4*)kg)[2 * j + 1];
                uint4 p;
                p.x = f2bf(x.x) | ((u32)f2bf(x.y) << 16);
                p.y = f2bf(x.z) | ((u32)f2bf(x.w) << 16);
                p.z = f2bf(y.x) | ((u32)f2bf(y.y) << 16);
                p.w = f2bf(y.z) | ((u32)f2bf(y.w) << 16);
                *(uint4*)&krow[(kst_g * 4 + j) * 8] = p;
            }
        }
        // ---- stage V transposed [dim][key], granule pos = (kgran + dim>>4)&7 ----
        {
            int key0 = kbase + 2 * vp2;
            int tok0 = k0 + (key0     < Lk ? key0     : Lk - 1);
            int tok1 = k0 + (key0 + 1 < Lk ? key0 + 1 : Lk - 1);
            const float* va = vv + ((size_t)tok0 * NUM_KV + kvh) * HD + vdg * 16;
            const float* vb = vv + ((size_t)tok1 * NUM_KV + kvh) * HD + vdg * 16;
            int pos = ((vgran + vdg) & 7) * 8 + vko;
#pragma unroll
            for (int i4 = 0; i4 < 4; ++i4) {
                float4 a = ((const float4*)va)[i4];
                float4 bb = ((const float4*)vb)[i4];
                int d0 = vdg * 16 + i4 * 4;
                *(u32*)&Vt[(d0 + 0) * VSTR + pos] = f2bf(a.x) | ((u32)f2bf(bb.x) << 16);
                *(u32*)&Vt[(d0 + 1) * VSTR + pos] = f2bf(a.y) | ((u32)f2bf(bb.y) << 16);
                *(u32*)&Vt[(d0 + 2) * VSTR + pos] = f2bf(a.z) | ((u32)f2bf(bb.z) << 16);
                *(u32*)&Vt[(d0 + 3) * VSTR + pos] = f2bf(a.w) | ((u32)f2bf(bb.w) << 16);
            }
        }
        __syncthreads();

        // ---- S = Q K^T ----
        f32x4 S[2][4];
#pragma unroll
        for (int rt = 0; rt < 2; ++rt)
#pragma unroll
            for (int nt = 0; nt < 4; ++nt) S[rt][nt] = (f32x4)(0.0f);
#pragma unroll
        for (int nt = 0; nt < 4; ++nt) {
            int key = nt * 16 + c;
#pragma unroll
            for (int kc = 0; kc < 4; ++kc) {
                bf16x8 kf = *(const bf16x8*)&Kt[key * KSTR + (kc * 4 + quad) * 8];
                S[0][nt] = __builtin_amdgcn_mfma_f32_16x16x32_bf16(qf[0][kc], kf, S[0][nt], 0, 0, 0);
                S[1][nt] = __builtin_amdgcn_mfma_f32_16x16x32_bf16(qf[1][kc], kf, S[1][nt], 0, 0, 0);
            }
        }

        // ---- online softmax; write P for both row-tiles, single LDS wait ----
        u16* pb = &Pb[wave * (32 * PSTR)];
#pragma unroll
        for (int rt = 0; rt < 2; ++rt) {
            int rtb = qbase + rt * 16;
            bool notfull = !((kbase + BN <= rtb + 1) && (kbase + BN <= Lk));
            if (notfull) {
                int qp4 = rtb + quad * 4;
#pragma unroll
                for (int nt = 0; nt < 4; ++nt) {
                    int kp = kbase + nt * 16 + c;
                    bool kval = kp < Lk;
#pragma unroll
                    for (int r = 0; r < 4; ++r)
                        if (!(kval && kp <= qp4 + r)) S[rt][nt][r] = -3.0e38f;
                }
            }
            f32x4 rm;
#pragma unroll
            for (int r = 0; r < 4; ++r)
                rm[r] = fmaxf(fmaxf(S[rt][0][r], S[rt][1][r]), fmaxf(S[rt][2][r], S[rt][3][r]));
#pragma unroll
            for (int d2 = 1; d2 < 16; d2 <<= 1)
#pragma unroll
                for (int r = 0; r < 4; ++r)
                    rm[r] = fmaxf(rm[r], __shfl_xor(rm[r], d2));
            f32x4 mn, al;
#pragma unroll
            for (int r = 0; r < 4; ++r) {
                mn[r] = fmaxf(m_i[rt][r], rm[r]);
                al[r] = exp2f(m_i[rt][r] - mn[r]);
            }
            m_i[rt] = mn;
            f32x4 rs = (f32x4)(0.0f);
#pragma unroll
            for (int nt = 0; nt < 4; ++nt)
#pragma unroll
                for (int r = 0; r < 4; ++r) {
                    float p = exp2f(S[rt][nt][r] - mn[r]);
                    S[rt][nt][r] = p;
                    rs[r] += p;
                }
#pragma unroll
            for (int d2 = 1; d2 < 16; d2 <<= 1)
#pragma unroll
                for (int r = 0; r < 4; ++r)
                    rs[r] += __shfl_xor(rs[r], d2);
#pragma unroll
            for (int r = 0; r < 4; ++r)
                l_i[rt][r] = l_i[rt][r] * al[r] + rs[r];
#pragma unroll
            for (int nt = 0; nt < 8; ++nt)
#pragma unroll
                for (int r = 0; r < 4; ++r)
                    Oacc[rt][nt][r] *= al[r];
#pragma unroll
            for (int nt = 0; nt < 4; ++nt)
#pragma unroll
                for (int r = 0; r < 4; ++r)
                    pb[(rt * 16 + quad * 4 + r) * PSTR + nt * 16 + c] = f2bf(S[rt][nt][r]);
        }
        asm volatile("s_waitcnt lgkmcnt(0)" ::: "memory");
        bf16x8 pf[2][2];
#pragma unroll
        for (int rt = 0; rt < 2; ++rt) {
            pf[rt][0] = *(const bf16x8*)&pb[(rt * 16 + c) * PSTR + quad * 8];
            pf[rt][1] = *(const bf16x8*)&pb[(rt * 16 + c) * PSTR + 32 + quad * 8];
        }
        asm volatile("" ::: "memory");

        // ---- O += P V ----
#pragma unroll
        for (int nt = 0; nt < 8; ++nt) {
            int dim = nt * 16 + c;
#pragma unroll
            for (int kc = 0; kc < 2; ++kc) {
                bf16x8 vf = *(const bf16x8*)&Vt[dim * VSTR + (((kc * 4 + quad) + nt) & 7) * 8];
                Oacc[0][nt] = __builtin_amdgcn_mfma_f32_16x16x32_bf16(pf[0][kc], vf, Oacc[0][nt], 0, 0, 0);
                Oacc[1][nt] = __builtin_amdgcn_mfma_f32_16x16x32_bf16(pf[1][kc], vf, Oacc[1][nt], 0, 0, 0);
            }
        }
    }

    // ---- epilogue: normalize and store ----
#pragma unroll
    for (int rt = 0; rt < 2; ++rt) {
        f32x4 li;
#pragma unroll
        for (int r = 0; r < 4; ++r) li[r] = 1.0f / l_i[rt][r];
#pragma unroll
        for (int r = 0; r < 4; ++r) {
            int row = qbase + rt * 16 + quad * 4 + r;
            if (row < Lq) {
                float* op = out + ((size_t)(q0 + row) * NUM_HEADS + h) * HD + c;
#pragma unroll
                for (int nt = 0; nt < 8; ++nt)
                    op[nt * 16] = Oacc[rt][nt][r] * li[r];
            }
        }
    }
}

extern "C" void kernel_launch(void* const* d_in, const int* in_sizes, int n_in,
                              void* d_out, int out_size, void* d_ws, size_t ws_size,
                              hipStream_t stream) {
    const float* q   = (const float*)d_in[0];
    const float* k   = (const float*)d_in[1];
    const float* v   = (const float*)d_in[2];
    const float* kci = (const float*)d_in[3];
    const float* vci = (const float*)d_in[4];
    const int* slot  = (const int*)d_in[5];
    const int* cuq   = (const int*)d_in[6];
    const int* cuk   = (const int*)d_in[7];

    int total  = in_sizes[0] / (NUM_HEADS * HD);
    int nslots = in_sizes[3] / (NUM_KV * HD);
    int nseq   = in_sizes[6] - 1;

    float* out = (float*)d_out;
    float* kco = out + (size_t)total * NUM_HEADS * HD;
    float* vco = kco + (size_t)nslots * NUM_KV * HD;

    int* inv = (int*)d_ws;
    int nattn = QTMAX * nseq * NUM_KV;
    int W = nattn / 2;
    if (W > 512) W = 512;

    inv_init<<<64, 256, 0, stream>>>(inv, nslots);
    inv_scatter<<<(total + 255) / 256, 256, 0, stream>>>(slot, inv, total, nslots);
    fused_kernel<<<nattn + W, 256, 0, stream>>>(q, k, v, kci, vci, inv, cuq, cuk,
                                                out, kco, vco, nseq, nslots, W, nattn);
}